// Round 1
// 174.669 us; speedup vs baseline: 1.0194x; 1.0194x over previous
//
#include <hip/hip_runtime.h>
#include <cstdint>

// ---------------- problem constants ----------------
#define H_IN   128
#define W_IN   128
#define C_IN   256
#define O_OUT  256
#define OH     126
#define OW     126

// ---------------- tiling ----------------
#define TY     16               // output tile height
#define TX     4                // output tile width
#define IR     (TY + 2)         // 18 input rows staged
#define ICOLS  (TX + 2)         // 6 input cols staged
#define NPIX   (IR * ICOLS)     // 108 staged pixels
#define SHW    258              // halfword stride per staged pixel (256 bf16 + 2 pad)
                                //   bank(px) = px*129 mod 32 -> 2-way (free)
#define IN_HW  (NPIX * SHW)     // 27864 halfwords = 55728 B input region
#define NWAVES 8
#define OPW    32               // output channels per wave
#define SST    34               // flush-stage word stride (even -> 8B-aligned float2)
#define STG_W  (64 * SST)       // 2176 words per wave
#define LDS_BYTES (NWAVES * STG_W * 4)   // 69632 B >= 55728 (flush reuses input region)
                                         // 2 blocks/CU: 139264 <= 163840 OK

// ---------------- prep: build padded channel-interleaved entry table ----------
// Channels grouped 8-wide: subgroup sg = o>>3 (32 subgroups, 4 per wave).
// Subgroup sg padded to S[sg] = max per-channel count; table row (slot) holds
// 8 entries (one per channel j=o&7), dummies are (meta=0, val=0).
// meta pre-scaled to BYTES so the hot loop is addr-add + lshl + fmac only.
__global__ void prep_kernel(const int* __restrict__ wi, const float* __restrict__ wv,
                            int nnz, int* __restrict__ sgS, int* __restrict__ sgBase,
                            int2* __restrict__ tab) {
    __shared__ int cnt[256];
    __shared__ int smax[32];
    __shared__ int sbase[33];
    __shared__ int is32;
    const int tid = threadIdx.x;
    cnt[tid] = 0;
    if (tid == 0) is32 = 0;
    __syncthreads();
    // dtype detect: int32 layout has nonzero odd words (ih/ic); int64 highs are 0
    int f = 0;
    for (int idx = tid * 2 + 1; idx < nnz * 4; idx += 512) f |= wi[idx];
    if (f) atomicOr(&is32, 1);
    __syncthreads();
    const int stride = is32 ? 4 : 8;
    const int step   = is32 ? 1 : 2;
    for (int e = tid; e < nnz; e += 256)
        atomicAdd(&cnt[wi[e * stride]], 1);
    __syncthreads();
    if (tid < 32) {
        int m = 0;
        for (int k = 0; k < 8; ++k) m = max(m, cnt[tid * 8 + k]);
        smax[tid] = m;
    }
    __syncthreads();
    if (tid == 0) {
        int s = 0;
        for (int i = 0; i < 32; ++i) { sbase[i] = s; s += 8 * smax[i]; }
        sbase[32] = s;
    }
    __syncthreads();
    const int T = sbase[32];
    for (int i = tid; i < T; i += 256) tab[i] = make_int2(0, 0);  // dummy: lds[A2+0] * 0.0f
    cnt[tid] = 0;            // reuse as per-channel slot cursor
    __syncthreads();
    for (int e = tid; e < nnz; e += 256) {
        int o  = wi[e * stride];
        int h  = wi[e * stride + 1 * step];
        int w_ = wi[e * stride + 2 * step];
        int c  = wi[e * stride + 3 * step];
        // faithful scrambled mapping: flat k in (kh,kw,C), reinterpreted as (C,kh,kw)
        int k   = h * 768 + w_ * 256 + c;
        int cp  = k / 9;
        int rem = k - cp * 9;
        int i_  = rem / 3;
        int j_  = rem - i_ * 3;
        int meta2 = (((i_ * ICOLS + j_) * SHW) + cp) * 2;   // LDS BYTE delta for tap/channel
        int slot = atomicAdd(&cnt[o], 1);                   // duplicates get distinct slots (summed)
        tab[sbase[o >> 3] + slot * 8 + (o & 7)] = make_int2(meta2, __float_as_int(wv[e]));
    }
    if (tid < 32) sgS[tid] = smax[tid];
    if (tid < 33) sgBase[tid] = sbase[tid];
}

// round-to-nearest-even fp32 -> bf16 bits
__device__ inline unsigned short rtne_bf16(float f) {
    unsigned u = __float_as_uint(f);
    u += 0x7FFFu + ((u >> 16) & 1u);
    return (unsigned short)(u >> 16);
}

__device__ __forceinline__ float bfld(const char* b, int off) {
    return __uint_as_float(((unsigned)*(const unsigned short*)(b + off)) << 16);
}

// ---------------- main conv kernel ----------------
__global__ __launch_bounds__(512, 4)
void conv_kernel(const float* __restrict__ in, float* __restrict__ out,
                 const int* __restrict__ sgS, const int* __restrict__ sgBase,
                 const int2* __restrict__ tab) {
    extern __shared__ char smem[];
    unsigned short* ldsH = (unsigned short*)smem;
    float*          ldsF = (float*)smem;

    const int tid  = threadIdx.x;
    const int w    = tid >> 6;
    const int lane = tid & 63;
    const int tx = blockIdx.x, ty = blockIdx.y, b = blockIdx.z;
    const int iy0 = ty * TY, ix0 = tx * TX;
    const float* inb = in + (size_t)b * (H_IN * W_IN * C_IN);

    // ---- stage input tile: 108 px x 256 ch fp32 -> bf16 in LDS ----
    // wave handles whole pixel: 64 lanes x float4 (1 KB coalesced read)
    for (int p = w; p < NPIX; p += NWAVES) {
        int r = p / ICOLS, c = p - r * ICOLS;
        int gy = iy0 + r, gx = ix0 + c;
        if (gy < H_IN && gx < W_IN) {          // wave-uniform
            const float4 v = *(const float4*)(inb + ((gy * W_IN + gx) << 8) + (lane << 2));
            ushort2 lo, hi;
            lo.x = rtne_bf16(v.x); lo.y = rtne_bf16(v.y);
            hi.x = rtne_bf16(v.z); hi.y = rtne_bf16(v.w);
            unsigned short* d = ldsH + p * SHW + (lane << 2);
            *(ushort2*)(d)     = lo;           // 4B-aligned b32 writes
            *(ushort2*)(d + 2) = hi;
        }
    }
    __syncthreads();

    // ---- gather: lane = output pixel; wave owns 32 channels in 4 subgroups of 8 ----
    // Each slot row = 8 independent {load -> ds_read -> fmac} chains with
    // compile-time acc indices: deep ILP, no per-channel pipeline drains.
    const int A2  = (((lane >> 2) * ICOLS + (lane & 3)) * SHW) * 2;  // byte base, 2-way banks
    const int sgb = w * 4;
    const char* basep = (const char*)smem;
    float acc[OPW];
#pragma unroll
    for (int i = 0; i < OPW; ++i) acc[i] = 0.f;

#pragma unroll
    for (int g = 0; g < 4; ++g) {
        const int S = sgS[sgb + g];
        const int2* Tg = tab + sgBase[sgb + g];
        for (int slot = 0; slot < S; ++slot) {
            const int4* R = (const int4*)(Tg + (slot << 3));   // 64 B contiguous, L1/L2-hot
            const int4 p0 = R[0];
            const int4 p1 = R[1];
            const int4 p2 = R[2];
            const int4 p3 = R[3];
            acc[g * 8 + 0] += __int_as_float(p0.y) * bfld(basep, A2 + p0.x);
            acc[g * 8 + 1] += __int_as_float(p0.w) * bfld(basep, A2 + p0.z);
            acc[g * 8 + 2] += __int_as_float(p1.y) * bfld(basep, A2 + p1.x);
            acc[g * 8 + 3] += __int_as_float(p1.w) * bfld(basep, A2 + p1.z);
            acc[g * 8 + 4] += __int_as_float(p2.y) * bfld(basep, A2 + p2.x);
            acc[g * 8 + 5] += __int_as_float(p2.w) * bfld(basep, A2 + p2.z);
            acc[g * 8 + 6] += __int_as_float(p3.y) * bfld(basep, A2 + p3.x);
            acc[g * 8 + 7] += __int_as_float(p3.w) * bfld(basep, A2 + p3.z);
        }
    }

    // ---- flush: input region is dead after this barrier; reuse as transpose stage ----
    __syncthreads();
    const int ob = w * OPW;
    {
        float* st = ldsF + w * STG_W + lane * SST;
#pragma unroll
        for (int k = 0; k < OPW; k += 2)
            *(float2*)(st + k) = make_float2(acc[k], acc[k + 1]);
    }
    __syncthreads();   // cross-lane transpose within wave region
    {
        const int a_  = lane >> 3;     // pixel sub-index 0..7
        const int chq = lane & 7;      // channel quad 0..7
        const float* rb = ldsF + w * STG_W;
#pragma unroll
        for (int s8 = 0; s8 < 8; ++s8) {
            int p = s8 * 8 + a_;
            float2 u0 = *(const float2*)(rb + p * SST + chq * 4);
            float2 u1 = *(const float2*)(rb + p * SST + chq * 4 + 2);
            int poy = iy0 + (p >> 2), pox = ix0 + (p & 3);
            if (poy < OH && pox < OW) {
                float4 o4 = make_float4(u0.x, u0.y, u1.x, u1.y);
                // 8 lanes per pixel -> 128 B contiguous segment
                *(float4*)(out + (((size_t)b * OH + poy) * OW + pox) * O_OUT + ob + chq * 4) = o4;
            }
        }
    }
}

// ---------------- host ----------------
extern "C" void kernel_launch(void* const* d_in, const int* in_sizes, int n_in,
                              void* d_out, int out_size, void* d_ws, size_t ws_size,
                              hipStream_t stream) {
    const float* input = (const float*)d_in[0];
    const int*   widx  = (const int*)d_in[1];    // int32 or int64 (runtime-detected)
    const float* wval  = (const float*)d_in[2];
    float* outp = (float*)d_out;
    const int nnz = in_sizes[2];
    const int B = in_sizes[0] / (H_IN * W_IN * C_IN);

    int*  sgS    = (int*)d_ws;                       // 32 ints
    int*  sgBase = sgS + 32;                         // 33 ints
    int2* tab    = (int2*)((char*)d_ws + 512);       // 16B-aligned; worst case 8*nnz entries

    prep_kernel<<<1, 256, 0, stream>>>(widx, wval, nnz, sgS, sgBase, tab);

    static_assert(LDS_BYTES >= NPIX * SHW * 2, "flush stage must cover input region");
    static_assert(LDS_BYTES <= 80 * 1024, "need 2 blocks/CU");
    hipFuncSetAttribute((const void*)conv_kernel,
                        hipFuncAttributeMaxDynamicSharedMemorySize, LDS_BYTES);
    dim3 grid((OW + TX - 1) / TX, (OH + TY - 1) / TY, B);
    conv_kernel<<<grid, 512, LDS_BYTES, stream>>>(input, outp, sgS, sgBase, tab);
}

// Round 2
// 149.627 us; speedup vs baseline: 1.1901x; 1.1674x over previous
//
#include <hip/hip_runtime.h>
#include <cstdint>

// ---------------- problem constants ----------------
#define H_IN   128
#define W_IN   128
#define C_IN   256
#define O_OUT  256
#define OH     126
#define OW     126

// ---------------- tiling ----------------
#define TY     8                // output tile height
#define TX     8                // output tile width  (64 px = 1 px/lane)
#define IR     (TY + 2)         // 10 input rows staged
#define ICOLS  (TX + 2)         // 10 input cols staged
#define NPIX   (IR * ICOLS)     // 100 staged pixels
#define SHW    258              // halfword stride per staged pixel (256 bf16 + 2 pad)
                                //   bank(px) = px*129 mod 32 = px mod 32 -> <=3-way
#define IN_BYTES (NPIX * SHW * 2)        // 51600 B input region
#define NWAVES 8
#define OPW    32               // output channels per wave
#define SST    34               // flush-stage word stride (even -> 8B-aligned float2)
#define STG_W  (64 * SST)       // 2176 words per wave
#define FLUSH_BYTES (4 * STG_W * 4)      // 34816 B: 4 waves per flush pass
#define LDS_BYTES IN_BYTES               // 51600 B -> 3 blocks/CU (154800 <= 163840)

// ---------------- prep: build padded channel-interleaved entry table ----------
// Channels grouped 8-wide: subgroup sg = o>>3 (32 subgroups, 4 per wave).
// Subgroup sg padded to S[sg] = max per-channel count; table row (slot) holds
// 8 entries (one per channel j=o&7), dummies are (meta=0, val=0).
// meta pre-scaled to BYTES so the hot loop is addr-add + fmac only.
__global__ void prep_kernel(const int* __restrict__ wi, const float* __restrict__ wv,
                            int nnz, int* __restrict__ sgS, int* __restrict__ sgBase,
                            int2* __restrict__ tab) {
    __shared__ int cnt[256];
    __shared__ int smax[32];
    __shared__ int sbase[33];
    __shared__ int is32;
    const int tid = threadIdx.x;
    cnt[tid] = 0;
    if (tid == 0) is32 = 0;
    __syncthreads();
    // dtype detect: int32 layout has nonzero odd words (ih/ic); int64 highs are 0
    int f = 0;
    for (int idx = tid * 2 + 1; idx < nnz * 4; idx += 512) f |= wi[idx];
    if (f) atomicOr(&is32, 1);
    __syncthreads();
    const int stride = is32 ? 4 : 8;
    const int step   = is32 ? 1 : 2;
    for (int e = tid; e < nnz; e += 256)
        atomicAdd(&cnt[wi[e * stride]], 1);
    __syncthreads();
    if (tid < 32) {
        int m = 0;
        for (int k = 0; k < 8; ++k) m = max(m, cnt[tid * 8 + k]);
        smax[tid] = m;
    }
    __syncthreads();
    if (tid == 0) {
        int s = 0;
        for (int i = 0; i < 32; ++i) { sbase[i] = s; s += 8 * smax[i]; }
        sbase[32] = s;
    }
    __syncthreads();
    const int T = sbase[32];
    for (int i = tid; i < T; i += 256) tab[i] = make_int2(0, 0);  // dummy: lds[A2+0] * 0.0f
    cnt[tid] = 0;            // reuse as per-channel slot cursor
    __syncthreads();
    for (int e = tid; e < nnz; e += 256) {
        int o  = wi[e * stride];
        int h  = wi[e * stride + 1 * step];
        int w_ = wi[e * stride + 2 * step];
        int c  = wi[e * stride + 3 * step];
        // faithful scrambled mapping: flat k in (kh,kw,C), reinterpreted as (C,kh,kw)
        int k   = h * 768 + w_ * 256 + c;
        int cp  = k / 9;
        int rem = k - cp * 9;
        int i_  = rem / 3;
        int j_  = rem - i_ * 3;
        int meta2 = (((i_ * ICOLS + j_) * SHW) + cp) * 2;   // LDS BYTE delta for tap/channel
        int slot = atomicAdd(&cnt[o], 1);                   // duplicates get distinct slots (summed)
        tab[sbase[o >> 3] + slot * 8 + (o & 7)] = make_int2(meta2, __float_as_int(wv[e]));
    }
    if (tid < 32) sgS[tid] = smax[tid];
    if (tid < 33) sgBase[tid] = sbase[tid];
}

// round-to-nearest-even fp32 -> bf16 bits
__device__ inline unsigned short rtne_bf16(float f) {
    unsigned u = __float_as_uint(f);
    u += 0x7FFFu + ((u >> 16) & 1u);
    return (unsigned short)(u >> 16);
}

__device__ __forceinline__ float bfld(const char* b, int off) {
    return __uint_as_float(((unsigned)*(const unsigned short*)(b + off)) << 16);
}

// ---------------- main conv kernel ----------------
// 3 blocks/CU (LDS 51600*3 <= 160K), 6 waves/SIMD -> VGPR budget 85
__global__ __launch_bounds__(512, 6)
void conv_kernel(const float* __restrict__ in, float* __restrict__ out,
                 const int* __restrict__ sgS, const int* __restrict__ sgBase,
                 const int2* __restrict__ tab) {
    extern __shared__ char smem[];
    unsigned short* ldsH = (unsigned short*)smem;
    float*          ldsF = (float*)smem;

    const int tid  = threadIdx.x;
    const int w    = __builtin_amdgcn_readfirstlane(tid >> 6);  // wave-uniform in SGPR
    const int lane = tid & 63;
    const int tx = blockIdx.x, ty = blockIdx.y, b = blockIdx.z;
    const int iy0 = ty * TY, ix0 = tx * TX;
    const float* inb = in + (size_t)b * (H_IN * W_IN * C_IN);

    // ---- stage input tile: 100 px x 256 ch fp32 -> bf16 in LDS ----
    // wave handles whole pixel: 64 lanes x float4 (1 KB coalesced read).
    // 4-deep load batching: issue 4 independent HBM loads, then convert/write,
    // so latency amortizes instead of a per-iteration vmcnt(0) chain.
    for (int base = 0; base < 16; base += 4) {
        float4 v[4];
#pragma unroll
        for (int q = 0; q < 4; ++q) {
            int p = w + (base + q) * NWAVES;
            if (p < NPIX) {
                int r = p / ICOLS, c = p - r * ICOLS;
                int gy = iy0 + r, gx = ix0 + c;
                if (gy < H_IN && gx < W_IN)   // wave-uniform
                    v[q] = *(const float4*)(inb + ((gy * W_IN + gx) << 8) + (lane << 2));
            }
        }
#pragma unroll
        for (int q = 0; q < 4; ++q) {
            int p = w + (base + q) * NWAVES;
            if (p < NPIX) {
                int r = p / ICOLS, c = p - r * ICOLS;
                int gy = iy0 + r, gx = ix0 + c;
                if (gy < H_IN && gx < W_IN) {
                    ushort2 lo, hi;
                    lo.x = rtne_bf16(v[q].x); lo.y = rtne_bf16(v[q].y);
                    hi.x = rtne_bf16(v[q].z); hi.y = rtne_bf16(v[q].w);
                    unsigned short* d = ldsH + p * SHW + (lane << 2);
                    *(ushort2*)(d)     = lo;           // 4B-aligned b32 writes
                    *(ushort2*)(d + 2) = hi;
                }
            }
        }
    }
    __syncthreads();

    // ---- gather: lane = output pixel (8x8); wave owns 32 ch in 4 subgroups of 8 ----
    const int A2  = (((lane >> 3) * ICOLS + (lane & 7)) * SHW) * 2;  // byte base
    const int sgb = w * 4;
    const char* basep = (const char*)smem;
    float acc[OPW];
#pragma unroll
    for (int i = 0; i < OPW; ++i) acc[i] = 0.f;

#pragma unroll
    for (int g = 0; g < 4; ++g) {
        const int S = sgS[sgb + g];
        const int2* Tg = tab + sgBase[sgb + g];
        for (int slot = 0; slot < S; ++slot) {
            const int4* R = (const int4*)(Tg + (slot << 3));   // 64 B, wave-uniform, cache-hot
            const int4 p0 = R[0];
            const int4 p1 = R[1];
            const int4 p2 = R[2];
            const int4 p3 = R[3];
            acc[g * 8 + 0] += __int_as_float(p0.y) * bfld(basep, A2 + p0.x);
            acc[g * 8 + 1] += __int_as_float(p0.w) * bfld(basep, A2 + p0.z);
            acc[g * 8 + 2] += __int_as_float(p1.y) * bfld(basep, A2 + p1.x);
            acc[g * 8 + 3] += __int_as_float(p1.w) * bfld(basep, A2 + p1.z);
            acc[g * 8 + 4] += __int_as_float(p2.y) * bfld(basep, A2 + p2.x);
            acc[g * 8 + 5] += __int_as_float(p2.w) * bfld(basep, A2 + p2.z);
            acc[g * 8 + 6] += __int_as_float(p3.y) * bfld(basep, A2 + p3.x);
            acc[g * 8 + 7] += __int_as_float(p3.w) * bfld(basep, A2 + p3.z);
        }
    }

    // ---- flush: input region dead; two passes of 4 waves reuse it as transpose stage ----
    __syncthreads();                                   // (B1) input region dead
    const int ob = w * OPW;
    const int wq = w & 3;
    // pass 0: waves 0-3
    if (w < 4) {
        float* st = ldsF + wq * STG_W + lane * SST;
#pragma unroll
        for (int k = 0; k < OPW; k += 2)
            *(float2*)(st + k) = make_float2(acc[k], acc[k + 1]);
    }
    __syncthreads();                                   // (B2)
    if (w < 4) {
        const int a_  = lane >> 3;     // pixel sub-index 0..7
        const int chq = lane & 7;      // channel quad 0..7
        const float* rb = ldsF + wq * STG_W;
#pragma unroll
        for (int s8 = 0; s8 < 8; ++s8) {
            int p = s8 * 8 + a_;
            float2 u0 = *(const float2*)(rb + p * SST + chq * 4);
            float2 u1 = *(const float2*)(rb + p * SST + chq * 4 + 2);
            int poy = iy0 + (p >> 3), pox = ix0 + (p & 7);
            if (poy < OH && pox < OW) {
                float4 o4 = make_float4(u0.x, u0.y, u1.x, u1.y);
                *(float4*)(out + (((size_t)b * OH + poy) * OW + pox) * O_OUT + ob + chq * 4) = o4;
            }
        }
    }
    __syncthreads();                                   // (B3) pass-0 reads done
    // pass 1: waves 4-7
    if (w >= 4) {
        float* st = ldsF + wq * STG_W + lane * SST;
#pragma unroll
        for (int k = 0; k < OPW; k += 2)
            *(float2*)(st + k) = make_float2(acc[k], acc[k + 1]);
    }
    __syncthreads();                                   // (B4)
    if (w >= 4) {
        const int a_  = lane >> 3;
        const int chq = lane & 7;
        const float* rb = ldsF + wq * STG_W;
#pragma unroll
        for (int s8 = 0; s8 < 8; ++s8) {
            int p = s8 * 8 + a_;
            float2 u0 = *(const float2*)(rb + p * SST + chq * 4);
            float2 u1 = *(const float2*)(rb + p * SST + chq * 4 + 2);
            int poy = iy0 + (p >> 3), pox = ix0 + (p & 7);
            if (poy < OH && pox < OW) {
                float4 o4 = make_float4(u0.x, u0.y, u1.x, u1.y);
                *(float4*)(out + (((size_t)b * OH + poy) * OW + pox) * O_OUT + ob + chq * 4) = o4;
            }
        }
    }
}

// ---------------- host ----------------
extern "C" void kernel_launch(void* const* d_in, const int* in_sizes, int n_in,
                              void* d_out, int out_size, void* d_ws, size_t ws_size,
                              hipStream_t stream) {
    const float* input = (const float*)d_in[0];
    const int*   widx  = (const int*)d_in[1];    // int32 or int64 (runtime-detected)
    const float* wval  = (const float*)d_in[2];
    float* outp = (float*)d_out;
    const int nnz = in_sizes[2];
    const int B = in_sizes[0] / (H_IN * W_IN * C_IN);

    int*  sgS    = (int*)d_ws;                       // 32 ints
    int*  sgBase = sgS + 32;                         // 33 ints
    int2* tab    = (int2*)((char*)d_ws + 512);       // 16B-aligned; worst case 8*nnz entries

    prep_kernel<<<1, 256, 0, stream>>>(widx, wval, nnz, sgS, sgBase, tab);

    static_assert(LDS_BYTES >= FLUSH_BYTES, "flush pass must fit in input region");
    static_assert(3 * LDS_BYTES <= 160 * 1024, "need 3 blocks/CU");
    hipFuncSetAttribute((const void*)conv_kernel,
                        hipFuncAttributeMaxDynamicSharedMemorySize, LDS_BYTES);
    dim3 grid((OW + TX - 1) / TX, (OH + TY - 1) / TY, B);
    conv_kernel<<<grid, 512, LDS_BYTES, stream>>>(input, outp, sgS, sgBase, tab);
}